// Round 20
// baseline (547.900 us; speedup 1.0000x reference)
//
#include <hip/hip_runtime.h>
#include <hip/hip_bf16.h>
#include <hip/hip_cooperative_groups.h>

namespace cg = cooperative_groups;

// Gram reassociation (no softmax in reference):
//   O_h = X_h * U_h,  U_h = M G Wv^T,  M = Wq^T Wk,  G = X_h^T X_h
// R20: R18's DAG as ONE cooperative kernel with OCCUPANCY-QUERIED grid
// (R19 failed because grid=1024 assumed 4 blk/CU; measured occupancy says
// ~2-3). All phases are grid-stride over virtual block ids. If the coop
// launch is rejected (API/capture), fall back to the R18 8-launch path —
// both paths are BIT-IDENTICAL math, so output is the same either way.
// Phases: P0 prep | P1 B1{G-tri splitK8 || M splitK2} | P2 redGM+mirror |
// P3 Yt=MG splitK4 | P4 redYt | P5 Ut=(Wv,Yt) splitK4 | P6 redUt | P7 O.
// Core: BK=64 + T2 XOR swizzle (rule #21), R11 fence discipline, LDS-staged
// coalesced epilogue — all proven through R18 (113.5us, absmax 42).

using bf16 = __hip_bfloat16;
typedef __attribute__((ext_vector_type(8))) __bf16 bf16x8;
typedef __attribute__((ext_vector_type(8))) unsigned short u16x8;
typedef __attribute__((ext_vector_type(4))) float f32x4;

#define M1 (1024 * 1024)

__device__ __forceinline__ void gload_lds16(const void* g, void* l) {
    __builtin_amdgcn_global_load_lds(
        (const __attribute__((address_space(1))) void*)g,
        (__attribute__((address_space(3))) void*)l, 16, 0, 0);
}

__device__ __forceinline__ void waitv0() {
    asm volatile("s_waitcnt vmcnt(0)" ::: "memory");
}

struct MegaArgs {
    const float* x;
    const float* w[4];    // Wq1, Wq2, Wk1, Wk2
    const float* wv[2];   // Wv1, Wv2
    bf16 *xb, *xt, *wdst, *Mp, *Mb, *Gb, *Ytb, *Utb;
    bf16* scr;            // d_out as scratch
    float* out;           // d_out as final output
};

// ---- shared GEMM core: C(+m0,n0 tile) = A B^T over Ksub, bt-form, BK=64 ----
template<int BM_, int BN_, typename OUT_T>
__device__ __forceinline__ void gemm_core(
    const bf16* __restrict__ A, int lda,
    const bf16* __restrict__ B, int ldb,
    OUT_T* __restrict__ C, int ldc,
    int m0, int n0, int Ksub,
    unsigned short* smem, int tid)
{
    constexpr int BK = 64;
    unsigned short* As = smem;
    unsigned short* Bs = smem + BM_ * BK;

    constexpr int MI = BM_ / 32;
    constexpr int NI = BN_ / 32;

    const int lane = tid & 63;
    const int wave = tid >> 6;
    const int wm   = wave >> 1;
    const int wn   = wave & 1;
    const int fr = lane & 15;
    const int kg = lane >> 4;

    const int srow  = tid >> 3;
    const int scol  = (tid & 7) * 8;
    const int scolg = scol ^ ((srow & 7) << 3);   // pre-swizzled global col

    f32x4 acc[MI][NI];
    #pragma unroll
    for (int i = 0; i < MI; ++i)
        #pragma unroll
        for (int j = 0; j < NI; ++j)
            acc[i][j] = {0.f, 0.f, 0.f, 0.f};

    const int niter = Ksub >> 6;
    for (int it = 0; it < niter; ++it) {
        const int kt = it << 6;
        #pragma unroll
        for (int r = 0; r < BM_ / 32; ++r)
            gload_lds16(A + (size_t)(m0 + r * 32 + srow) * lda + (kt + scolg),
                        &As[(r * 32 + srow) * BK + scol]);
        #pragma unroll
        for (int r = 0; r < BN_ / 32; ++r)
            gload_lds16(B + (size_t)(n0 + r * 32 + srow) * ldb + (kt + scolg),
                        &Bs[(r * 32 + srow) * BK + scol]);
        waitv0();
        __builtin_amdgcn_s_barrier();
        __builtin_amdgcn_sched_barrier(0);

        #pragma unroll
        for (int kk = 0; kk < 2; ++kk) {
            bf16x8 af[MI], bfg[NI];
            #pragma unroll
            for (int mi = 0; mi < MI; ++mi) {
                const int row = wm * (BM_ / 2) + mi * 16 + fr;
                const int c = (kk * 32 + kg * 8) ^ ((row & 7) << 3);
                af[mi] = *(const bf16x8*)&As[row * BK + c];
            }
            #pragma unroll
            for (int ni = 0; ni < NI; ++ni) {
                const int row = wn * (BN_ / 2) + ni * 16 + fr;
                const int c = (kk * 32 + kg * 8) ^ ((row & 7) << 3);
                bfg[ni] = *(const bf16x8*)&Bs[row * BK + c];
            }
            #pragma unroll
            for (int mi = 0; mi < MI; ++mi)
                #pragma unroll
                for (int ni = 0; ni < NI; ++ni)
                    acc[mi][ni] = __builtin_amdgcn_mfma_f32_16x16x32_bf16(
                        af[mi], bfg[ni], acc[mi][ni], 0, 0, 0);
        }

        __builtin_amdgcn_sched_barrier(0);
        __builtin_amdgcn_s_barrier();
        __builtin_amdgcn_sched_barrier(0);
    }

    // epilogue: acc -> LDS tile -> coalesced stores
    // C/D layout: col = lane&15, row = (lane>>4)*4 + j  [m89-verified]
    if constexpr (sizeof(OUT_T) == 2) {
        #pragma unroll
        for (int mi = 0; mi < MI; ++mi)
            #pragma unroll
            for (int ni = 0; ni < NI; ++ni) {
                const int c = wn * (BN_ / 2) + ni * 16 + fr;
                #pragma unroll
                for (int j = 0; j < 4; ++j) {
                    const int r = wm * (BM_ / 2) + mi * 16 + kg * 4 + j;
                    bf16 h = __float2bfloat16(acc[mi][ni][j]);
                    smem[r * BN_ + c] = *(unsigned short*)&h;
                }
            }
        __syncthreads();
        constexpr int V = (BM_ * BN_) / 2048;
        #pragma unroll
        for (int v = 0; v < V; ++v) {
            const int off = v * 2048 + tid * 8;
            const int r = off / BN_;
            const int c = off % BN_;
            *(u16x8*)((unsigned short*)C + (size_t)(m0 + r) * ldc + n0 + c) =
                *(const u16x8*)&smem[off];
        }
    } else {
        float* fs = (float*)smem;
        #pragma unroll
        for (int mi = 0; mi < MI; ++mi)
            #pragma unroll
            for (int ni = 0; ni < NI; ++ni) {
                const int c = wn * (BN_ / 2) + ni * 16 + fr;
                #pragma unroll
                for (int j = 0; j < 4; ++j) {
                    const int r = wm * (BM_ / 2) + mi * 16 + kg * 4 + j;
                    fs[r * BN_ + c] = acc[mi][ni][j];
                }
            }
        __syncthreads();
        constexpr int V = (BM_ * BN_) / 1024;
        #pragma unroll
        for (int v = 0; v < V; ++v) {
            const int off = v * 1024 + tid * 4;
            const int r = off / BN_;
            const int c = off % BN_;
            *(float4*)((float*)C + (size_t)(m0 + r) * ldc + n0 + c) =
                *(const float4*)&fs[off];
        }
    }
    __syncthreads();   // smem safe for next use
}

// ---------------- small helpers ----------------

__device__ __forceinline__ ushort4 cvt4(float4 v) {
    ushort4 o; bf16 h;
    h = __float2bfloat16(v.x); o.x = *(unsigned short*)&h;
    h = __float2bfloat16(v.y); o.y = *(unsigned short*)&h;
    h = __float2bfloat16(v.z); o.z = *(unsigned short*)&h;
    h = __float2bfloat16(v.w); o.w = *(unsigned short*)&h;
    return o;
}

__device__ void xpose64(const float* __restrict__ src, int ldsrc,
                        int r0, int c0,
                        bf16* __restrict__ dstS, int ldS,
                        bf16* __restrict__ dstT, int ldT,
                        float (*tile)[65], int t)
{
    const int tr  = t >> 4;
    const int tc4 = (t & 15) * 4;
    #pragma unroll
    for (int ph = 0; ph < 4; ++ph) {
        const int row = ph * 16 + tr;
        float4 v = *(const float4*)(src + (size_t)(r0 + row) * ldsrc + c0 + tc4);
        tile[row][tc4 + 0] = v.x;
        tile[row][tc4 + 1] = v.y;
        tile[row][tc4 + 2] = v.z;
        tile[row][tc4 + 3] = v.w;
        if (dstS)
            *(ushort4*)((unsigned short*)dstS + (size_t)(r0 + row) * ldS + c0 + tc4) = cvt4(v);
    }
    __syncthreads();
    #pragma unroll
    for (int ph = 0; ph < 4; ++ph) {
        const int crow = ph * 16 + tr;
        float4 v = {tile[tc4 + 0][crow], tile[tc4 + 1][crow],
                    tile[tc4 + 2][crow], tile[tc4 + 3][crow]};
        *(ushort4*)((unsigned short*)dstT + (size_t)(c0 + crow) * ldT + r0 + tc4) = cvt4(v);
    }
    __syncthreads();
}

__device__ __forceinline__ void reduce_slices(const unsigned short* src,
                                              unsigned short* dst,
                                              int h, int r, int nslice)
{
    float acc[8] = {0, 0, 0, 0, 0, 0, 0, 0};
    for (int s = 0; s < nslice; ++s) {
        u16x8 v = *(const u16x8*)(src + ((size_t)(h * nslice + s) << 20) + r);
        #pragma unroll
        for (int j = 0; j < 8; ++j)
            acc[j] += __uint_as_float(((unsigned)v[j]) << 16);
    }
    u16x8 o;
    #pragma unroll
    for (int j = 0; j < 8; ++j) {
        bf16 hh = __float2bfloat16(acc[j]);
        o[j] = *(unsigned short*)&hh;
    }
    *(u16x8*)(dst + ((size_t)h << 20) + r) = o;
}

// ---------------- phase bodies (shared by mega + fallback) ----------------

__device__ void phase_prep(const MegaArgs& a, int vb, int tid, unsigned short* smem)
{
    float (*tile)[65] = (float(*)[65])smem;
    if (vb < 2048) {
        const int n0 = (vb & 63) * 64;
        const int c0 = (vb >> 6) * 64;
        xpose64(a.x, 2048, n0, c0, a.xb, 2048, a.xt, 4096, tile, tid);
    } else if (vb < 3072) {
        const int idx = vb - 2048;
        const int mat = idx >> 8;
        const int tl  = idx & 255;
        xpose64(a.w[mat], 1024, (tl & 15) * 64, (tl >> 4) * 64,
                nullptr, 0, a.wdst + (size_t)mat * M1, 1024, tile, tid);
    } else {
        const int idx = vb - 3072;
        const int mat = idx >> 9;
        const int blk = idx & 511;
        const size_t off = (size_t)blk * 2048 + tid * 8;
        float4 v0 = *(const float4*)(a.wv[mat] + off);
        float4 v1 = *(const float4*)(a.wv[mat] + off + 4);
        unsigned short* d = (unsigned short*)a.wdst + (size_t)(4 + mat) * M1 + off;
        *(ushort4*)d       = cvt4(v0);
        *(ushort4*)(d + 4) = cvt4(v1);
    }
}

__device__ void phase_b1(const MegaArgs& a, int wg, int tid, unsigned short* smem)
{
    if (wg < 576) {
        const int z = wg / 36;
        const int tile = wg - z * 36;
        const int h = z >> 3, s = z & 7;
        int ti = 0, rem = tile;
        while (rem >= 8 - ti) { rem -= 8 - ti; ++ti; }
        const int tj = ti + rem;
        gemm_core<128, 128, bf16>(
            a.xt + (size_t)(h * 1024 + ti * 128) * 4096 + s * 512, 4096,
            a.xt + (size_t)(h * 1024 + tj * 128) * 4096 + s * 512, 4096,
            a.scr + ((size_t)z * 36 + tile) * 16384, 128,
            0, 0, 512, smem, tid);
    } else {
        const int idx = wg - 576;
        const int combo = idx >> 6;          // h*2+s
        const int h = combo >> 1, s = combo & 1;
        const int tile = idx & 63;
        // M = gemm_bt(WqT, WkT) = Wq^T Wk  (R13-proven operand order)
        gemm_core<128, 128, bf16>(
            a.wdst + (size_t)h * M1 + s * 512, 1024,
            a.wdst + (size_t)(2 + h) * M1 + s * 512, 1024,
            a.Mp + (size_t)combo * M1, 1024,
            (tile >> 3) * 128, (tile & 7) * 128, 512, smem, tid);
    }
}

__device__ void phase_redgm(const MegaArgs& a, int b, int tid)
{
    if (b < 576) {
        const int h    = b / 288;
        const int rem  = b - h * 288;
        const int tile = rem >> 3;
        const int blk  = rem & 7;
        int ti = 0, trem = tile;
        while (trem >= 8 - ti) { trem -= 8 - ti; ++ti; }
        const int tj = ti + trem;
        const int e  = blk * 2048 + tid * 8;
        const int r  = e >> 7;
        const int c0 = e & 127;
        float acc[8] = {0, 0, 0, 0, 0, 0, 0, 0};
        for (int s = 0; s < 8; ++s) {
            u16x8 v = *(const u16x8*)((const unsigned short*)a.scr +
                      ((size_t)(h * 8 + s) * 36 + tile) * 16384 + e);
            #pragma unroll
            for (int j = 0; j < 8; ++j)
                acc[j] += __uint_as_float(((unsigned)v[j]) << 16);
        }
        u16x8 o;
        #pragma unroll
        for (int j = 0; j < 8; ++j) {
            bf16 hh = __float2bfloat16(acc[j]);
            o[j] = *(unsigned short*)&hh;
        }
        unsigned short* G = (unsigned short*)a.Gb + (size_t)h * M1;
        *(u16x8*)(G + (size_t)(ti * 128 + r) * 1024 + tj * 128 + c0) = o;
        if (ti != tj) {
            #pragma unroll
            for (int j = 0; j < 8; ++j)
                G[(size_t)(tj * 128 + c0 + j) * 1024 + ti * 128 + r] = o[j];
        }
    } else {
        const int e = ((b - 576) * 256 + tid) * 8;
        reduce_slices((const unsigned short*)a.Mp, (unsigned short*)a.Mb,
                      e >> 20, e & (M1 - 1), 2);
    }
}

__device__ void phase_l4(const MegaArgs& a, int wg, int tid, unsigned short* smem)
{
    const int bx = wg & 7, by = (wg >> 3) & 7, z = wg >> 6;
    const int h = z >> 2, s = z & 3;
    gemm_core<128, 128, bf16>(
        a.Mb + (size_t)h * M1 + s * 256, 1024,
        a.Gb + (size_t)h * M1 + s * 256, 1024,
        a.scr + (size_t)z * M1, 1024,
        by * 128, bx * 128, 256, smem, tid);
}

__device__ void phase_redyt(const MegaArgs& a, int b, int tid)
{
    const int e = (b * 256 + tid) * 8;
    reduce_slices((const unsigned short*)a.scr, (unsigned short*)a.Ytb,
                  e >> 20, e & (M1 - 1), 4);
}

__device__ void phase_l6(const MegaArgs& a, int wg, int tid, unsigned short* smem)
{
    const int bx = wg & 7, by = (wg >> 3) & 7, z = wg >> 6;
    const int h = z >> 2, s = z & 3;
    gemm_core<128, 128, bf16>(
        a.wdst + (size_t)(4 + h) * M1 + s * 256, 1024,
        a.Ytb + (size_t)h * M1 + s * 256, 1024,
        a.scr + (size_t)z * M1, 1024,
        by * 128, bx * 128, 256, smem, tid);
}

__device__ void phase_redut(const MegaArgs& a, int b, int tid)
{
    const int e = (b * 256 + tid) * 8;
    reduce_slices((const unsigned short*)a.scr, (unsigned short*)a.Utb,
                  e >> 20, e & (M1 - 1), 4);
}

__device__ void phase_o(const MegaArgs& a, int wg, int tid, unsigned short* smem)
{
    const int bx = wg & 15, by = (wg >> 4) & 31, z = wg >> 9;
    gemm_core<128, 64, float>(
        a.xb + (size_t)z * 1024, 2048,
        a.Utb + (size_t)z * M1, 1024,
        a.out + (size_t)z * 1024, 2048,
        by * 128, bx * 64, 1024, smem, tid);
}

// ---------------- the mega kernel (cooperative) ----------------

__global__ __launch_bounds__(256, 4)
void mega(MegaArgs a)
{
    cg::grid_group grd = cg::this_grid();
    __shared__ __align__(16) unsigned short smem[16384];   // 32 KB
    const int tid = threadIdx.x;
    const int G = gridDim.x;                 // multiple of 256
    const int wg0 = (blockIdx.x & 7) * (G >> 3) + (blockIdx.x >> 3);

    for (int vb = wg0; vb < 4096; vb += G) phase_prep(a, vb, tid, smem);
    grd.sync();
    for (int vb = wg0; vb < 832; vb += G)  phase_b1(a, vb, tid, smem);
    grd.sync();
    for (int vb = wg0; vb < 1600; vb += G) phase_redgm(a, vb, tid);
    grd.sync();
    for (int vb = wg0; vb < 512; vb += G)  phase_l4(a, vb, tid, smem);
    grd.sync();
    for (int vb = wg0; vb < 1024; vb += G) phase_redyt(a, vb, tid);
    grd.sync();
    for (int vb = wg0; vb < 512; vb += G)  phase_l6(a, vb, tid, smem);
    grd.sync();
    for (int vb = wg0; vb < 1024; vb += G) phase_redut(a, vb, tid);
    grd.sync();
    for (int vb = wg0; vb < 1024; vb += G) phase_o(a, vb, tid, smem);
}

// ---------------- fallback wrappers (R18 path, bit-identical math) ----------

__global__ __launch_bounds__(256, 4) void k_prep(MegaArgs a) {
    __shared__ __align__(16) unsigned short smem[16384];
    phase_prep(a, blockIdx.x, threadIdx.x, smem);
}
__global__ __launch_bounds__(256, 4) void k_b1(MegaArgs a) {
    __shared__ __align__(16) unsigned short smem[16384];
    const int wg = (blockIdx.x & 7) * 104 + (blockIdx.x >> 3);   // nwg=832
    phase_b1(a, wg, threadIdx.x, smem);
}
__global__ void k_redgm(MegaArgs a) { phase_redgm(a, blockIdx.x, threadIdx.x); }
__global__ __launch_bounds__(256, 4) void k_l4(MegaArgs a) {
    __shared__ __align__(16) unsigned short smem[16384];
    const int wg = (blockIdx.x & 7) * 64 + (blockIdx.x >> 3);    // nwg=512
    phase_l4(a, wg, threadIdx.x, smem);
}
__global__ void k_redyt(MegaArgs a) { phase_redyt(a, blockIdx.x, threadIdx.x); }
__global__ __launch_bounds__(256, 4) void k_l6(MegaArgs a) {
    __shared__ __align__(16) unsigned short smem[16384];
    const int wg = (blockIdx.x & 7) * 64 + (blockIdx.x >> 3);
    phase_l6(a, wg, threadIdx.x, smem);
}
__global__ void k_redut(MegaArgs a) { phase_redut(a, blockIdx.x, threadIdx.x); }
__global__ __launch_bounds__(256, 4) void k_o(MegaArgs a) {
    __shared__ __align__(16) unsigned short smem[16384];
    const int wg = (blockIdx.x & 7) * 128 + (blockIdx.x >> 3);   // nwg=1024
    phase_o(a, wg, threadIdx.x, smem);
}

// ---------------- driver ----------------

extern "C" void kernel_launch(void* const* d_in, const int* in_sizes, int n_in,
                              void* d_out, int out_size, void* d_ws, size_t ws_size,
                              hipStream_t stream)
{
    // ws layout (bf16 elems): 34M elems = 68 MB
    bf16* xb   = (bf16*)d_ws;
    bf16* xt   = xb + 8 * M1;
    bf16* wdst = xt + 8 * M1;
    bf16* Mp   = wdst + 6 * M1;
    bf16* Mb   = Mp + 4 * M1;
    bf16* Gb   = Mb + 2 * M1;
    bf16* Ytb  = Gb + 2 * M1;
    bf16* Utb  = Ytb + 2 * M1;

    MegaArgs a;
    a.x = (const float*)d_in[0];
    a.w[0] = (const float*)d_in[1];  a.w[1] = (const float*)d_in[2];
    a.w[2] = (const float*)d_in[3];  a.w[3] = (const float*)d_in[4];
    a.wv[0] = (const float*)d_in[5]; a.wv[1] = (const float*)d_in[6];
    a.xb = xb; a.xt = xt; a.wdst = wdst;
    a.Mp = Mp; a.Mb = Mb; a.Gb = Gb; a.Ytb = Ytb; a.Utb = Utb;
    a.scr = (bf16*)d_out;
    a.out = (float*)d_out;

    // Cooperative path: grid sized from the occupancy QUERY (R19 lesson:
    // never assume max residency). Falls back to the 8-launch R18 path on
    // any failure — both paths compute bit-identical results.
    bool done = false;
    int occ = 0;
    if (hipOccupancyMaxActiveBlocksPerMultiprocessor(
            &occ, (const void*)mega, 256, 0) == hipSuccess && occ > 0) {
        int grid = occ * 256;
        if (grid > 1024) grid = 1024;
        if (grid >= 256) {
            void* args[] = {&a};
            if (hipLaunchCooperativeKernel((const void*)mega, dim3(grid),
                                           dim3(256), args, 0, stream) == hipSuccess)
                done = true;
        }
    }

    if (!done) {
        k_prep<<<4096, 256, 0, stream>>>(a);
        k_b1<<<832, 256, 0, stream>>>(a);
        k_redgm<<<1600, 256, 0, stream>>>(a);
        k_l4<<<512, 256, 0, stream>>>(a);
        k_redyt<<<1024, 256, 0, stream>>>(a);
        k_l6<<<512, 256, 0, stream>>>(a);
        k_redut<<<1024, 256, 0, stream>>>(a);
        k_o<<<1024, 256, 0, stream>>>(a);
    }
}

// Round 21
// 110.774 us; speedup vs baseline: 4.9461x; 4.9461x over previous
//
#include <hip/hip_runtime.h>
#include <hip/hip_bf16.h>

// Gram reassociation (no softmax in reference):
//   O_h = X_h * U_h,  U_h = M G Wv^T,  M = Wq^T Wk,  G = X_h^T X_h
// R21 = the R18-proven 8-launch DAG (113.5us, absmax 42), expressed via
// shared phase bodies (compile-proven in R20's fallback). Coop fusion
// REMOVED: R20 measured grid.sync() at ~100us/sync on MI355X (mega 975us,
// all pipes idle) — launch boundaries in the captured graph are ~30x cheaper.
// Phases: P0 prep | P1 B1{G-tri splitK8 || M splitK2, uniform 8-iter} |
// P2 redGM+mirror | P3 Yt=MG splitK4 | P4 redYt | P5 Ut=(Wv,Yt) splitK4 |
// P6 redUt | P7 O -> f32 out.
// Core: BK=64 + T2 XOR swizzle (rule #21: pre-swizzled global src + same
// XOR on LDS read), R11 s_barrier+sched_barrier fence discipline, LDS-staged
// coalesced epilogue, XCD-chunked block swizzle.

using bf16 = __hip_bfloat16;
typedef __attribute__((ext_vector_type(8))) __bf16 bf16x8;
typedef __attribute__((ext_vector_type(8))) unsigned short u16x8;
typedef __attribute__((ext_vector_type(4))) float f32x4;

#define M1 (1024 * 1024)

__device__ __forceinline__ void gload_lds16(const void* g, void* l) {
    __builtin_amdgcn_global_load_lds(
        (const __attribute__((address_space(1))) void*)g,
        (__attribute__((address_space(3))) void*)l, 16, 0, 0);
}

__device__ __forceinline__ void waitv0() {
    asm volatile("s_waitcnt vmcnt(0)" ::: "memory");
}

struct MegaArgs {
    const float* x;
    const float* w[4];    // Wq1, Wq2, Wk1, Wk2
    const float* wv[2];   // Wv1, Wv2
    bf16 *xb, *xt, *wdst, *Mp, *Mb, *Gb, *Ytb, *Utb;
    bf16* scr;            // d_out as scratch
    float* out;           // d_out as final output
};

// ---- shared GEMM core: C(+m0,n0 tile) = A B^T over Ksub, bt-form, BK=64 ----
template<int BM_, int BN_, typename OUT_T>
__device__ __forceinline__ void gemm_core(
    const bf16* __restrict__ A, int lda,
    const bf16* __restrict__ B, int ldb,
    OUT_T* __restrict__ C, int ldc,
    int m0, int n0, int Ksub,
    unsigned short* smem, int tid)
{
    constexpr int BK = 64;
    unsigned short* As = smem;
    unsigned short* Bs = smem + BM_ * BK;

    constexpr int MI = BM_ / 32;
    constexpr int NI = BN_ / 32;

    const int lane = tid & 63;
    const int wave = tid >> 6;
    const int wm   = wave >> 1;
    const int wn   = wave & 1;
    const int fr = lane & 15;
    const int kg = lane >> 4;

    const int srow  = tid >> 3;
    const int scol  = (tid & 7) * 8;
    const int scolg = scol ^ ((srow & 7) << 3);   // pre-swizzled global col

    f32x4 acc[MI][NI];
    #pragma unroll
    for (int i = 0; i < MI; ++i)
        #pragma unroll
        for (int j = 0; j < NI; ++j)
            acc[i][j] = {0.f, 0.f, 0.f, 0.f};

    const int niter = Ksub >> 6;
    for (int it = 0; it < niter; ++it) {
        const int kt = it << 6;
        #pragma unroll
        for (int r = 0; r < BM_ / 32; ++r)
            gload_lds16(A + (size_t)(m0 + r * 32 + srow) * lda + (kt + scolg),
                        &As[(r * 32 + srow) * BK + scol]);
        #pragma unroll
        for (int r = 0; r < BN_ / 32; ++r)
            gload_lds16(B + (size_t)(n0 + r * 32 + srow) * ldb + (kt + scolg),
                        &Bs[(r * 32 + srow) * BK + scol]);
        waitv0();
        __builtin_amdgcn_s_barrier();
        __builtin_amdgcn_sched_barrier(0);

        #pragma unroll
        for (int kk = 0; kk < 2; ++kk) {
            bf16x8 af[MI], bfg[NI];
            #pragma unroll
            for (int mi = 0; mi < MI; ++mi) {
                const int row = wm * (BM_ / 2) + mi * 16 + fr;
                const int c = (kk * 32 + kg * 8) ^ ((row & 7) << 3);
                af[mi] = *(const bf16x8*)&As[row * BK + c];
            }
            #pragma unroll
            for (int ni = 0; ni < NI; ++ni) {
                const int row = wn * (BN_ / 2) + ni * 16 + fr;
                const int c = (kk * 32 + kg * 8) ^ ((row & 7) << 3);
                bfg[ni] = *(const bf16x8*)&Bs[row * BK + c];
            }
            #pragma unroll
            for (int mi = 0; mi < MI; ++mi)
                #pragma unroll
                for (int ni = 0; ni < NI; ++ni)
                    acc[mi][ni] = __builtin_amdgcn_mfma_f32_16x16x32_bf16(
                        af[mi], bfg[ni], acc[mi][ni], 0, 0, 0);
        }

        __builtin_amdgcn_sched_barrier(0);
        __builtin_amdgcn_s_barrier();
        __builtin_amdgcn_sched_barrier(0);
    }

    // epilogue: acc -> LDS tile -> coalesced stores
    // C/D layout: col = lane&15, row = (lane>>4)*4 + j  [m89-verified]
    if constexpr (sizeof(OUT_T) == 2) {
        #pragma unroll
        for (int mi = 0; mi < MI; ++mi)
            #pragma unroll
            for (int ni = 0; ni < NI; ++ni) {
                const int c = wn * (BN_ / 2) + ni * 16 + fr;
                #pragma unroll
                for (int j = 0; j < 4; ++j) {
                    const int r = wm * (BM_ / 2) + mi * 16 + kg * 4 + j;
                    bf16 h = __float2bfloat16(acc[mi][ni][j]);
                    smem[r * BN_ + c] = *(unsigned short*)&h;
                }
            }
        __syncthreads();
        constexpr int V = (BM_ * BN_) / 2048;
        #pragma unroll
        for (int v = 0; v < V; ++v) {
            const int off = v * 2048 + tid * 8;
            const int r = off / BN_;
            const int c = off % BN_;
            *(u16x8*)((unsigned short*)C + (size_t)(m0 + r) * ldc + n0 + c) =
                *(const u16x8*)&smem[off];
        }
    } else {
        float* fs = (float*)smem;
        #pragma unroll
        for (int mi = 0; mi < MI; ++mi)
            #pragma unroll
            for (int ni = 0; ni < NI; ++ni) {
                const int c = wn * (BN_ / 2) + ni * 16 + fr;
                #pragma unroll
                for (int j = 0; j < 4; ++j) {
                    const int r = wm * (BM_ / 2) + mi * 16 + kg * 4 + j;
                    fs[r * BN_ + c] = acc[mi][ni][j];
                }
            }
        __syncthreads();
        constexpr int V = (BM_ * BN_) / 1024;
        #pragma unroll
        for (int v = 0; v < V; ++v) {
            const int off = v * 1024 + tid * 4;
            const int r = off / BN_;
            const int c = off % BN_;
            *(float4*)((float*)C + (size_t)(m0 + r) * ldc + n0 + c) =
                *(const float4*)&fs[off];
        }
    }
}

// ---------------- small helpers ----------------

__device__ __forceinline__ ushort4 cvt4(float4 v) {
    ushort4 o; bf16 h;
    h = __float2bfloat16(v.x); o.x = *(unsigned short*)&h;
    h = __float2bfloat16(v.y); o.y = *(unsigned short*)&h;
    h = __float2bfloat16(v.z); o.z = *(unsigned short*)&h;
    h = __float2bfloat16(v.w); o.w = *(unsigned short*)&h;
    return o;
}

__device__ void xpose64(const float* __restrict__ src, int ldsrc,
                        int r0, int c0,
                        bf16* __restrict__ dstS, int ldS,
                        bf16* __restrict__ dstT, int ldT,
                        float (*tile)[65], int t)
{
    const int tr  = t >> 4;
    const int tc4 = (t & 15) * 4;
    #pragma unroll
    for (int ph = 0; ph < 4; ++ph) {
        const int row = ph * 16 + tr;
        float4 v = *(const float4*)(src + (size_t)(r0 + row) * ldsrc + c0 + tc4);
        tile[row][tc4 + 0] = v.x;
        tile[row][tc4 + 1] = v.y;
        tile[row][tc4 + 2] = v.z;
        tile[row][tc4 + 3] = v.w;
        if (dstS)
            *(ushort4*)((unsigned short*)dstS + (size_t)(r0 + row) * ldS + c0 + tc4) = cvt4(v);
    }
    __syncthreads();
    #pragma unroll
    for (int ph = 0; ph < 4; ++ph) {
        const int crow = ph * 16 + tr;
        float4 v = {tile[tc4 + 0][crow], tile[tc4 + 1][crow],
                    tile[tc4 + 2][crow], tile[tc4 + 3][crow]};
        *(ushort4*)((unsigned short*)dstT + (size_t)(c0 + crow) * ldT + r0 + tc4) = cvt4(v);
    }
}

__device__ __forceinline__ void reduce_slices(const unsigned short* src,
                                              unsigned short* dst,
                                              int h, int r, int nslice)
{
    float acc[8] = {0, 0, 0, 0, 0, 0, 0, 0};
    for (int s = 0; s < nslice; ++s) {
        u16x8 v = *(const u16x8*)(src + ((size_t)(h * nslice + s) << 20) + r);
        #pragma unroll
        for (int j = 0; j < 8; ++j)
            acc[j] += __uint_as_float(((unsigned)v[j]) << 16);
    }
    u16x8 o;
    #pragma unroll
    for (int j = 0; j < 8; ++j) {
        bf16 hh = __float2bfloat16(acc[j]);
        o[j] = *(unsigned short*)&hh;
    }
    *(u16x8*)(dst + ((size_t)h << 20) + r) = o;
}

// ---------------- phase bodies ----------------

__device__ void phase_prep(const MegaArgs& a, int vb, int tid, unsigned short* smem)
{
    float (*tile)[65] = (float(*)[65])smem;
    if (vb < 2048) {
        const int n0 = (vb & 63) * 64;
        const int c0 = (vb >> 6) * 64;
        xpose64(a.x, 2048, n0, c0, a.xb, 2048, a.xt, 4096, tile, tid);
    } else if (vb < 3072) {
        const int idx = vb - 2048;
        const int mat = idx >> 8;
        const int tl  = idx & 255;
        xpose64(a.w[mat], 1024, (tl & 15) * 64, (tl >> 4) * 64,
                nullptr, 0, a.wdst + (size_t)mat * M1, 1024, tile, tid);
    } else {
        const int idx = vb - 3072;
        const int mat = idx >> 9;
        const int blk = idx & 511;
        const size_t off = (size_t)blk * 2048 + tid * 8;
        float4 v0 = *(const float4*)(a.wv[mat] + off);
        float4 v1 = *(const float4*)(a.wv[mat] + off + 4);
        unsigned short* d = (unsigned short*)a.wdst + (size_t)(4 + mat) * M1 + off;
        *(ushort4*)d       = cvt4(v0);
        *(ushort4*)(d + 4) = cvt4(v1);
    }
}

__device__ void phase_b1(const MegaArgs& a, int wg, int tid, unsigned short* smem)
{
    if (wg < 576) {
        const int z = wg / 36;
        const int tile = wg - z * 36;
        const int h = z >> 3, s = z & 7;
        int ti = 0, rem = tile;
        while (rem >= 8 - ti) { rem -= 8 - ti; ++ti; }
        const int tj = ti + rem;
        gemm_core<128, 128, bf16>(
            a.xt + (size_t)(h * 1024 + ti * 128) * 4096 + s * 512, 4096,
            a.xt + (size_t)(h * 1024 + tj * 128) * 4096 + s * 512, 4096,
            a.scr + ((size_t)z * 36 + tile) * 16384, 128,
            0, 0, 512, smem, tid);
    } else {
        const int idx = wg - 576;
        const int combo = idx >> 6;          // h*2+s
        const int h = combo >> 1, s = combo & 1;
        const int tile = idx & 63;
        // M = gemm_bt(WqT, WkT) = Wq^T Wk  (R13-proven operand order)
        gemm_core<128, 128, bf16>(
            a.wdst + (size_t)h * M1 + s * 512, 1024,
            a.wdst + (size_t)(2 + h) * M1 + s * 512, 1024,
            a.Mp + (size_t)combo * M1, 1024,
            (tile >> 3) * 128, (tile & 7) * 128, 512, smem, tid);
    }
}

__device__ void phase_redgm(const MegaArgs& a, int b, int tid)
{
    if (b < 576) {
        const int h    = b / 288;
        const int rem  = b - h * 288;
        const int tile = rem >> 3;
        const int blk  = rem & 7;
        int ti = 0, trem = tile;
        while (trem >= 8 - ti) { trem -= 8 - ti; ++ti; }
        const int tj = ti + trem;
        const int e  = blk * 2048 + tid * 8;
        const int r  = e >> 7;
        const int c0 = e & 127;
        float acc[8] = {0, 0, 0, 0, 0, 0, 0, 0};
        for (int s = 0; s < 8; ++s) {
            u16x8 v = *(const u16x8*)((const unsigned short*)a.scr +
                      ((size_t)(h * 8 + s) * 36 + tile) * 16384 + e);
            #pragma unroll
            for (int j = 0; j < 8; ++j)
                acc[j] += __uint_as_float(((unsigned)v[j]) << 16);
        }
        u16x8 o;
        #pragma unroll
        for (int j = 0; j < 8; ++j) {
            bf16 hh = __float2bfloat16(acc[j]);
            o[j] = *(unsigned short*)&hh;
        }
        unsigned short* G = (unsigned short*)a.Gb + (size_t)h * M1;
        *(u16x8*)(G + (size_t)(ti * 128 + r) * 1024 + tj * 128 + c0) = o;
        if (ti != tj) {
            #pragma unroll
            for (int j = 0; j < 8; ++j)
                G[(size_t)(tj * 128 + c0 + j) * 1024 + ti * 128 + r] = o[j];
        }
    } else {
        const int e = ((b - 576) * 256 + tid) * 8;
        reduce_slices((const unsigned short*)a.Mp, (unsigned short*)a.Mb,
                      e >> 20, e & (M1 - 1), 2);
    }
}

__device__ void phase_l4(const MegaArgs& a, int wg, int tid, unsigned short* smem)
{
    const int bx = wg & 7, by = (wg >> 3) & 7, z = wg >> 6;
    const int h = z >> 2, s = z & 3;
    gemm_core<128, 128, bf16>(
        a.Mb + (size_t)h * M1 + s * 256, 1024,
        a.Gb + (size_t)h * M1 + s * 256, 1024,
        a.scr + (size_t)z * M1, 1024,
        by * 128, bx * 128, 256, smem, tid);
}

__device__ void phase_redyt(const MegaArgs& a, int b, int tid)
{
    const int e = (b * 256 + tid) * 8;
    reduce_slices((const unsigned short*)a.scr, (unsigned short*)a.Ytb,
                  e >> 20, e & (M1 - 1), 4);
}

__device__ void phase_l6(const MegaArgs& a, int wg, int tid, unsigned short* smem)
{
    const int bx = wg & 7, by = (wg >> 3) & 7, z = wg >> 6;
    const int h = z >> 2, s = z & 3;
    gemm_core<128, 128, bf16>(
        a.wdst + (size_t)(4 + h) * M1 + s * 256, 1024,
        a.Ytb + (size_t)h * M1 + s * 256, 1024,
        a.scr + (size_t)z * M1, 1024,
        by * 128, bx * 128, 256, smem, tid);
}

__device__ void phase_redut(const MegaArgs& a, int b, int tid)
{
    const int e = (b * 256 + tid) * 8;
    reduce_slices((const unsigned short*)a.scr, (unsigned short*)a.Utb,
                  e >> 20, e & (M1 - 1), 4);
}

__device__ void phase_o(const MegaArgs& a, int wg, int tid, unsigned short* smem)
{
    const int bx = wg & 15, by = (wg >> 4) & 31, z = wg >> 9;
    gemm_core<128, 64, float>(
        a.xb + (size_t)z * 1024, 2048,
        a.Utb + (size_t)z * M1, 1024,
        a.out + (size_t)z * 1024, 2048,
        by * 128, bx * 64, 1024, smem, tid);
}

// ---------------- kernels (one per phase, XCD-swizzled grids) ----------------

__global__ __launch_bounds__(256, 4) void k_prep(MegaArgs a) {
    __shared__ __align__(16) unsigned short smem[16384];
    phase_prep(a, blockIdx.x, threadIdx.x, smem);
}
__global__ __launch_bounds__(256, 4) void k_b1(MegaArgs a) {
    __shared__ __align__(16) unsigned short smem[16384];
    const int wg = (blockIdx.x & 7) * 104 + (blockIdx.x >> 3);   // nwg=832
    phase_b1(a, wg, threadIdx.x, smem);
}
__global__ void k_redgm(MegaArgs a) { phase_redgm(a, blockIdx.x, threadIdx.x); }
__global__ __launch_bounds__(256, 4) void k_l4(MegaArgs a) {
    __shared__ __align__(16) unsigned short smem[16384];
    const int wg = (blockIdx.x & 7) * 64 + (blockIdx.x >> 3);    // nwg=512
    phase_l4(a, wg, threadIdx.x, smem);
}
__global__ void k_redyt(MegaArgs a) { phase_redyt(a, blockIdx.x, threadIdx.x); }
__global__ __launch_bounds__(256, 4) void k_l6(MegaArgs a) {
    __shared__ __align__(16) unsigned short smem[16384];
    const int wg = (blockIdx.x & 7) * 64 + (blockIdx.x >> 3);
    phase_l6(a, wg, threadIdx.x, smem);
}
__global__ void k_redut(MegaArgs a) { phase_redut(a, blockIdx.x, threadIdx.x); }
__global__ __launch_bounds__(256, 4) void k_o(MegaArgs a) {
    __shared__ __align__(16) unsigned short smem[16384];
    const int wg = (blockIdx.x & 7) * 128 + (blockIdx.x >> 3);   // nwg=1024
    phase_o(a, wg, threadIdx.x, smem);
}

// ---------------- driver ----------------

extern "C" void kernel_launch(void* const* d_in, const int* in_sizes, int n_in,
                              void* d_out, int out_size, void* d_ws, size_t ws_size,
                              hipStream_t stream)
{
    // ws layout (bf16 elems): 34M elems = 68 MB
    bf16* xb   = (bf16*)d_ws;
    bf16* xt   = xb + 8 * M1;
    bf16* wdst = xt + 8 * M1;
    bf16* Mp   = wdst + 6 * M1;
    bf16* Mb   = Mp + 4 * M1;
    bf16* Gb   = Mb + 2 * M1;
    bf16* Ytb  = Gb + 2 * M1;
    bf16* Utb  = Ytb + 2 * M1;

    MegaArgs a;
    a.x = (const float*)d_in[0];
    a.w[0] = (const float*)d_in[1];  a.w[1] = (const float*)d_in[2];
    a.w[2] = (const float*)d_in[3];  a.w[3] = (const float*)d_in[4];
    a.wv[0] = (const float*)d_in[5]; a.wv[1] = (const float*)d_in[6];
    a.xb = xb; a.xt = xt; a.wdst = wdst;
    a.Mp = Mp; a.Mb = Mb; a.Gb = Gb; a.Ytb = Ytb; a.Utb = Utb;
    a.scr = (bf16*)d_out;
    a.out = (float*)d_out;

    k_prep<<<4096, 256, 0, stream>>>(a);
    k_b1<<<832, 256, 0, stream>>>(a);
    k_redgm<<<1600, 256, 0, stream>>>(a);
    k_l4<<<512, 256, 0, stream>>>(a);
    k_redyt<<<1024, 256, 0, stream>>>(a);
    k_l6<<<512, 256, 0, stream>>>(a);
    k_redut<<<1024, 256, 0, stream>>>(a);
    k_o<<<1024, 256, 0, stream>>>(a);
}